// Round 16
// baseline (331.221 us; speedup 1.0000x reference)
//
#include <hip/hip_runtime.h>
#include <hip/hip_bf16.h>
#include <stdint.h>

#define B_  256
#define C_  512
#define S_  256
#define NH  8
#define DH  64

typedef float f32x4 __attribute__((ext_vector_type(4)));
typedef short s16x8 __attribute__((ext_vector_type(8)));

static __device__ __forceinline__ unsigned short f2bf(float f) {
  union { float f; unsigned u; } v; v.f = f;
  unsigned r = v.u + 0x7FFFu + ((v.u >> 16) & 1u);
  return (unsigned short)(r >> 16);
}

static __device__ __forceinline__ unsigned pk_bf16(float lo, float hi) {
  unsigned r;
  asm("v_cvt_pk_bf16_f32 %0, %1, %2" : "=v"(r) : "v"(lo), "v"(hi));
  return r;
}

static __device__ __forceinline__ void gload_lds16(const void* g, void* l) {
  __builtin_amdgcn_global_load_lds((const __attribute__((address_space(1))) void*)g,
                                   (__attribute__((address_space(3))) void*)l,
                                   16, 0, 0);
}

// ---- prep (fused): blocks 0..8191 do x->xs transpose; 8192..8447 do W->bf16
__global__ __launch_bounds__(256) void prep(const float* __restrict__ x,
                                            const float* __restrict__ Wq,
                                            const float* __restrict__ Wk,
                                            const float* __restrict__ Wv,
                                            const float* __restrict__ Wf,
                                            unsigned short* __restrict__ Whead,
                                            unsigned short* __restrict__ Wft,
                                            unsigned short* __restrict__ xs) {
  __shared__ float tile[64][65];
  int bid = blockIdx.x;
  int t = threadIdx.x;
  int tr = t >> 4;          // 0..15
  int tc = (t & 15) * 4;    // 0..60
  if (bid < 8192) {
    int b = bid >> 5, rem = bid & 31;
    int s0 = (rem & 3) * 64, c0 = (rem >> 2) * 64;
    const float* xb = x + (size_t)b * C_ * S_;
#pragma unroll
    for (int i = 0; i < 4; ++i) {
      int c = tr + i * 16;
      float4 v = *(const float4*)&xb[(size_t)(c0 + c) * S_ + s0 + tc];
      tile[c][tc + 0] = v.x; tile[c][tc + 1] = v.y;
      tile[c][tc + 2] = v.z; tile[c][tc + 3] = v.w;
    }
    __syncthreads();
    unsigned short* xsb = xs + (size_t)b * S_ * C_;
#pragma unroll
    for (int i = 0; i < 4; ++i) {
      int s = tr + i * 16;
      ushort4 o;
      o.x = f2bf(tile[tc + 0][s]); o.y = f2bf(tile[tc + 1][s]);
      o.z = f2bf(tile[tc + 2][s]); o.w = f2bf(tile[tc + 3][s]);
      *(ushort4*)&xsb[(size_t)(s0 + s) * C_ + c0 + tc] = o;
    }
  } else {
    int r = bid - 8192;
    int mat = r >> 6, r6 = r & 63;
    int n0 = (r6 & 7) * 64, c0 = (r6 >> 3) * 64;
    const float* src = (mat == 0) ? Wq : (mat == 1) ? Wk : (mat == 2) ? Wv : Wf;
#pragma unroll
    for (int i = 0; i < 4; ++i) {
      int c = tr + i * 16;
      float4 v = *(const float4*)&src[(size_t)(c0 + c) * 512 + n0 + tc];
      tile[c][tc + 0] = v.x; tile[c][tc + 1] = v.y;
      tile[c][tc + 2] = v.z; tile[c][tc + 3] = v.w;
    }
    __syncthreads();
    int h = n0 >> 6;
    unsigned short* dst = (mat < 3) ? (Whead + ((size_t)h * 192 + mat * 64) * 512)
                                    : (Wft + (size_t)n0 * 512);
#pragma unroll
    for (int i = 0; i < 4; ++i) {
      int nl = tr + i * 16;
      ushort4 o;
      o.x = f2bf(tile[tc + 0][nl]); o.y = f2bf(tile[tc + 1][nl]);
      o.z = f2bf(tile[tc + 2][nl]); o.w = f2bf(tile[tc + 3][nl]);
      *(ushort4*)&dst[(size_t)nl * 512 + c0 + tc] = o;
    }
  }
}

// ------ qkvattn (R12/R13-best, FROZEN): fused QKV-GEMM + flash attention --
#define QKP 68
#define QOFF 0
#define KOFF 34816
#define VOFF 69632
__global__ __launch_bounds__(512) void qkvattn(const unsigned short* __restrict__ xs,
                                               const unsigned short* __restrict__ Whead,
                                               const float* __restrict__ bq,
                                               const float* __restrict__ bk,
                                               const float* __restrict__ bv,
                                               unsigned short* __restrict__ o) {
  __shared__ __align__(16) char lds[114688];
  int bid = blockIdx.x;
  int lin = (bid & 7) * 256 + (bid >> 3);
  int h = lin & 7, b = lin >> 3;
  int t = threadIdx.x, lane = t & 63, w = t >> 6;
  int l15 = lane & 15, l4 = lane >> 4;
  int wr = w >> 2, wc = w & 3;
  const unsigned short* xsb = xs + (size_t)b * S_ * C_;
  const unsigned short* wh  = Whead + (size_t)h * 192 * C_;

#define FSTAGE(kt, p)                                                         \
  {                                                                           \
    _Pragma("unroll")                                                         \
    for (int i = 0; i < 4; ++i) {                                             \
      int ch = i * 512 + t, r = ch >> 3, g = ch & 7;                          \
      int gs = g ^ (r & 7);                                                   \
      gload_lds16(xsb + (size_t)r * C_ + (kt) * 64 + gs * 8,                  \
                  lds + (p) * 57344 + ch * 16);                               \
    }                                                                         \
    _Pragma("unroll")                                                         \
    for (int i = 0; i < 3; ++i) {                                             \
      int ch = i * 512 + t, r = ch >> 3, g = ch & 7;                          \
      int gs = g ^ (r & 7);                                                   \
      gload_lds16(wh + (size_t)r * C_ + (kt) * 64 + gs * 8,                   \
                  lds + (p) * 57344 + 32768 + ch * 16);                       \
    }                                                                         \
  }

  f32x4 acc[8][3] = {};
  FSTAGE(0, 0);

  for (int kt = 0; kt < 8; ++kt) {
    if (kt < 7) FSTAGE(kt + 1, (kt + 1) & 1);
    if (kt < 7) asm volatile("s_waitcnt vmcnt(7)" ::: "memory");
    else        asm volatile("s_waitcnt vmcnt(0)" ::: "memory");
    __builtin_amdgcn_s_barrier();
    asm volatile("" ::: "memory");
    const char* Ab = lds + (kt & 1) * 57344;
    const char* Bb = Ab + 32768;
#pragma unroll
    for (int kk = 0; kk < 2; ++kk) {
      s16x8 afr[8], bfr[3];
#pragma unroll
      for (int fi = 0; fi < 8; ++fi) {
        int r = wr * 128 + fi * 16 + l15;
        afr[fi] = *(const s16x8*)(Ab + r * 128 + (((kk * 4 + l4) ^ (r & 7)) << 4));
      }
#pragma unroll
      for (int fj = 0; fj < 3; ++fj) {
        int r = wc * 48 + fj * 16 + l15;
        bfr[fj] = *(const s16x8*)(Bb + r * 128 + (((kk * 4 + l4) ^ (r & 7)) << 4));
      }
      __builtin_amdgcn_s_setprio(1);
#pragma unroll
      for (int fi = 0; fi < 8; ++fi)
#pragma unroll
        for (int fj = 0; fj < 3; ++fj)
          acc[fi][fj] = __builtin_amdgcn_mfma_f32_16x16x32_bf16(afr[fi], bfr[fj], acc[fi][fj], 0, 0, 0);
      __builtin_amdgcn_s_setprio(0);
    }
    __builtin_amdgcn_s_barrier();
  }
#undef FSTAGE

  unsigned short* Ql = (unsigned short*)(lds + QOFF);
  unsigned short* Kl = (unsigned short*)(lds + KOFF);
  unsigned short* Vl = (unsigned short*)(lds + VOFF);
  int h64 = h * 64;
#pragma unroll
  for (int fj = 0; fj < 3; ++fj) {
    int n = wc * 48 + fj * 16 + l15;
    int sel = n >> 6, d = n & 63;
    const float* bias = (sel == 0) ? bq : (sel == 1) ? bk : bv;
    float bias_v = bias[h64 + d];
    if (sel == 2) {
#pragma unroll
      for (int fi = 0; fi < 8; ++fi) {
        int s0 = wr * 128 + fi * 16 + l4 * 4;
        ushort4 o4;
        o4.x = f2bf(acc[fi][fj][0] + bias_v);
        o4.y = f2bf(acc[fi][fj][1] + bias_v);
        o4.z = f2bf(acc[fi][fj][2] + bias_v);
        o4.w = f2bf(acc[fi][fj][3] + bias_v);
        *(ushort4*)&Vl[d * 264 + s0] = o4;
      }
    } else {
      unsigned short* dstl = (sel == 0) ? Ql : Kl;
#pragma unroll
      for (int fi = 0; fi < 8; ++fi)
#pragma unroll
        for (int rg = 0; rg < 4; ++rg) {
          int s = wr * 128 + fi * 16 + l4 * 4 + rg;
          int row = s;
          if (sel == 1) {
            int s64 = s & 63, w32 = s64 & 31;
            row = (s & 192) + (s64 >> 5) * 32 + ((w32 >> 2) & 1) * 16 + (w32 >> 3) * 4 + (w32 & 3);
          }
          dstl[row * QKP + d] = f2bf(acc[fi][fj][rg] + bias_v);
        }
    }
  }
  __syncthreads();

  s16x8 qf[2][2];
#pragma unroll
  for (int fi = 0; fi < 2; ++fi)
#pragma unroll
    for (int kk = 0; kk < 2; ++kk) {
      int row = w * 32 + fi * 16 + l15;
      qf[fi][kk] = *(const s16x8*)((const char*)lds + QOFF + row * (QKP * 2) + kk * 64 + l4 * 16);
    }

  f32x4 acco[4][2] = {};
  float m_run[2] = {-3e38f, -3e38f}, l_run[2] = {0.f, 0.f};
  const float SCL = 0.125f * 1.44269504089f;

  for (int kb = 0; kb < 4; ++kb) {
    f32x4 accs[4][2] = {};
#pragma unroll
    for (int kk = 0; kk < 2; ++kk) {
      s16x8 kf[4];
#pragma unroll
      for (int fj = 0; fj < 4; ++fj)
        kf[fj] = *(const s16x8*)((const char*)lds + KOFF + (kb * 64 + fj * 16 + l15) * (QKP * 2) + kk * 64 + l4 * 16);
      __builtin_amdgcn_s_setprio(1);
#pragma unroll
      for (int fj = 0; fj < 4; ++fj)
#pragma unroll
        for (int fi = 0; fi < 2; ++fi)
          accs[fj][fi] = __builtin_amdgcn_mfma_f32_16x16x32_bf16(kf[fj], qf[fi][kk], accs[fj][fi], 0, 0, 0);
      __builtin_amdgcn_s_setprio(0);
    }
#pragma unroll
    for (int fi = 0; fi < 2; ++fi) {
      float m0[4];
#pragma unroll
      for (int fj = 0; fj < 4; ++fj)
        m0[fj] = fmaxf(fmaxf(accs[fj][fi][0], accs[fj][fi][1]),
                       fmaxf(accs[fj][fi][2], accs[fj][fi][3]));
      float mx = fmaxf(fmaxf(m0[0], m0[1]), fmaxf(m0[2], m0[3]));
      mx = fmaxf(mx, __shfl_xor(mx, 16, 64));
      mx = fmaxf(mx, __shfl_xor(mx, 32, 64));
      float mnew = fmaxf(m_run[fi], mx);
      float alpha = __builtin_amdgcn_exp2f((m_run[fi] - mnew) * SCL);
      m_run[fi] = mnew;
      float s0[4];
#pragma unroll
      for (int fj = 0; fj < 4; ++fj) {
#pragma unroll
        for (int rg = 0; rg < 4; ++rg) {
          float p = __builtin_amdgcn_exp2f((accs[fj][fi][rg] - mnew) * SCL);
          accs[fj][fi][rg] = p;
        }
        s0[fj] = (accs[fj][fi][0] + accs[fj][fi][1]) + (accs[fj][fi][2] + accs[fj][fi][3]);
      }
      float lsum = (s0[0] + s0[1]) + (s0[2] + s0[3]);
      lsum += __shfl_xor(lsum, 16, 64);
      lsum += __shfl_xor(lsum, 32, 64);
      l_run[fi] = l_run[fi] * alpha + lsum;
#pragma unroll
      for (int fd = 0; fd < 4; ++fd)
#pragma unroll
        for (int rg = 0; rg < 4; ++rg) acco[fd][fi][rg] *= alpha;
    }
#pragma unroll
    for (int kk2 = 0; kk2 < 2; ++kk2) {
      s16x8 vf[4];
#pragma unroll
      for (int fd = 0; fd < 4; ++fd)
        vf[fd] = *(const s16x8*)((const char*)lds + VOFF + (fd * 16 + l15) * 528 + kb * 128 + kk2 * 64 + l4 * 16);
#pragma unroll
      for (int fi = 0; fi < 2; ++fi) {
        union { unsigned u[4]; s16x8 v; } pb;
        pb.u[0] = pk_bf16(accs[2 * kk2][fi][0],     accs[2 * kk2][fi][1]);
        pb.u[1] = pk_bf16(accs[2 * kk2][fi][2],     accs[2 * kk2][fi][3]);
        pb.u[2] = pk_bf16(accs[2 * kk2 + 1][fi][0], accs[2 * kk2 + 1][fi][1]);
        pb.u[3] = pk_bf16(accs[2 * kk2 + 1][fi][2], accs[2 * kk2 + 1][fi][3]);
        __builtin_amdgcn_s_setprio(1);
#pragma unroll
        for (int fd = 0; fd < 4; ++fd)
          acco[fd][fi] = __builtin_amdgcn_mfma_f32_16x16x32_bf16(vf[fd], pb.v, acco[fd][fi], 0, 0, 0);
        __builtin_amdgcn_s_setprio(0);
      }
    }
  }

  unsigned short* ob = o + (size_t)b * S_ * C_ + h * DH;
#pragma unroll
  for (int fi = 0; fi < 2; ++fi) {
    float inv = 1.0f / l_run[fi];
    int qrow = w * 32 + fi * 16 + l15;
#pragma unroll
    for (int fd = 0; fd < 4; ++fd) {
      ushort4 s4;
      s4.x = f2bf(acco[fd][fi][0] * inv);
      s4.y = f2bf(acco[fd][fi][1] * inv);
      s4.z = f2bf(acco[fd][fi][2] * inv);
      s4.w = f2bf(acco[fd][fi][3] * inv);
      *(ushort4*)&ob[(size_t)qrow * C_ + fd * 16 + l4 * 4] = s4;
    }
  }
}

// ------- proj_gn v7: 64c x 256s, BK=64, 80KB LDS = 2 blocks/CU ------------
// 8 K-steps (16 MFMA/gate), uniform 5 loads/thread -> vmcnt(5); reduction
// arrays aliased into dead staging LDS after the K-loop.
__global__ __launch_bounds__(512, 4) void proj_gn(const unsigned short* __restrict__ o,
                                                  const unsigned short* __restrict__ Wft,
                                                  const float* __restrict__ bfp,
                                                  const float* __restrict__ x,
                                                  const float* __restrict__ gnw,
                                                  const float* __restrict__ gnb,
                                                  float* __restrict__ out) {
  __shared__ __align__(16) char plds[81920];   // 2 bufs x (A 8KB + B 32KB)
  int bid = blockIdx.x;
  int lin = (bid & 7) * 256 + (bid >> 3);   // XCD-chunked (2048 % 8 == 0)
  int b = lin >> 3, ct = lin & 7;           // each XCD: 32 b's, all 8 ct
  int t = threadIdx.x, lane = t & 63, w = t >> 6;
  int l15 = lane & 15, l4 = lane >> 4;
  f32x4 acc[4][2] = {};
  const unsigned short* wt = Wft + (size_t)ct * 64 * C_;    // A: 64 x 512
  const unsigned short* ob = o + (size_t)b * S_ * C_;       // B: 256 x 512

#define PSTAGE(kt, p)                                                         \
  {                                                                           \
    {                                                                         \
      int ch = t, r = ch >> 3, g = ch & 7;                                    \
      int gs = g ^ (r & 7);                                                   \
      gload_lds16(wt + (size_t)r * C_ + (kt) * 64 + gs * 8,                   \
                  plds + (p) * 40960 + ch * 16);                              \
    }                                                                         \
    _Pragma("unroll")                                                         \
    for (int i = 0; i < 4; ++i) {                                             \
      int ch = i * 512 + t, r = ch >> 3, g = ch & 7;                          \
      int gs = g ^ (r & 7);                                                   \
      gload_lds16(ob + (size_t)r * C_ + (kt) * 64 + gs * 8,                   \
                  plds + (p) * 40960 + 8192 + ch * 16);                       \
    }                                                                         \
  }

  PSTAGE(0, 0);

  for (int kt = 0; kt < 8; ++kt) {
    if (kt < 7) {
      PSTAGE(kt + 1, (kt + 1) & 1);
      asm volatile("s_waitcnt vmcnt(5)" ::: "memory");
    } else {
      asm volatile("s_waitcnt vmcnt(0)" ::: "memory");
    }
    __builtin_amdgcn_s_barrier();
    asm volatile("" ::: "memory");
    const char* Ab = plds + (kt & 1) * 40960;
    const char* Bb = Ab + 8192;
#pragma unroll
    for (int kk = 0; kk < 2; ++kk) {
      s16x8 af[4], bfr[2];
#pragma unroll
      for (int fi = 0; fi < 4; ++fi) {
        int r = fi * 16 + l15;
        af[fi] = *(const s16x8*)(Ab + r * 128 + (((kk * 4 + l4) ^ (r & 7)) << 4));
      }
#pragma unroll
      for (int fj = 0; fj < 2; ++fj) {
        int r = w * 32 + fj * 16 + l15;
        bfr[fj] = *(const s16x8*)(Bb + r * 128 + (((kk * 4 + l4) ^ (r & 7)) << 4));
      }
      __builtin_amdgcn_s_setprio(1);
#pragma unroll
      for (int fi = 0; fi < 4; ++fi)
#pragma unroll
        for (int fj = 0; fj < 2; ++fj)
          acc[fi][fj] = __builtin_amdgcn_mfma_f32_16x16x32_bf16(af[fi], bfr[fj], acc[fi][fj], 0, 0, 0);
      __builtin_amdgcn_s_setprio(0);
    }
    __builtin_amdgcn_s_barrier();
  }
#undef PSTAGE

  // reduction arrays alias the (now dead) staging LDS
  float* red_s = (float*)plds;
  float* red_q = (float*)(plds + 256);
  float* mu_s  = (float*)(plds + 512);
  float* rs_s  = (float*)(plds + 528);
  __syncthreads();
  if (t < 64) { red_s[t] = 0.f; red_q[t] = 0.f; }
  __syncthreads();

  const float* xb = x + (size_t)b * C_ * S_;
  int c_base = ct * 64;
  int s_base = w * 32;
#pragma unroll
  for (int fi = 0; fi < 4; ++fi)
#pragma unroll
    for (int rg = 0; rg < 4; ++rg) {
      int cl = fi * 16 + l4 * 4 + rg;
      int c = c_base + cl;
      float bias_v = bfp[c];
      float psum = 0.f, psq = 0.f;
#pragma unroll
      for (int fj = 0; fj < 2; ++fj) {
        int s = s_base + fj * 16 + l15;
        float y = acc[fi][fj][rg] + bias_v + xb[(size_t)c * S_ + s];
        acc[fi][fj][rg] = y;
        psum += y; psq += y * y;
      }
#pragma unroll
      for (int off = 1; off < 16; off <<= 1) {
        psum += __shfl_xor(psum, off, 64);
        psq += __shfl_xor(psq, off, 64);
      }
      if (l15 == 0) {
        atomicAdd(&red_s[cl], psum);
        atomicAdd(&red_q[cl], psq);
      }
    }
  __syncthreads();
  if (t < 4) {
    float s = 0.f, qq = 0.f;
#pragma unroll
    for (int i = 0; i < 16; ++i) { s += red_s[t * 16 + i]; qq += red_q[t * 16 + i]; }
    float mu = s * (1.0f / 4096.0f);
    float var = qq * (1.0f / 4096.0f) - mu * mu;
    mu_s[t] = mu;
    rs_s[t] = rsqrtf(var + 1e-5f);
  }
  __syncthreads();
  float* outb = out + (size_t)b * C_ * S_;
#pragma unroll
  for (int fi = 0; fi < 4; ++fi)
#pragma unroll
    for (int rg = 0; rg < 4; ++rg) {
      int cl = fi * 16 + l4 * 4 + rg;
      int c = c_base + cl;
      int gl = cl >> 4;
      float mu = mu_s[gl], rs = rs_s[gl];
      float gw = gnw[c], gb = gnb[c];
#pragma unroll
      for (int fj = 0; fj < 2; ++fj) {
        int s = s_base + fj * 16 + l15;
        outb[(size_t)c * S_ + s] = (acc[fi][fj][rg] - mu) * rs * gw + gb;
      }
    }
}

extern "C" void kernel_launch(void* const* d_in, const int* in_sizes, int n_in,
                              void* d_out, int out_size, void* d_ws, size_t ws_size,
                              hipStream_t stream) {
  const float* x   = (const float*)d_in[0];
  const float* Wq  = (const float*)d_in[1];
  const float* bq  = (const float*)d_in[2];
  const float* Wk  = (const float*)d_in[3];
  const float* bk  = (const float*)d_in[4];
  const float* Wv  = (const float*)d_in[5];
  const float* bv  = (const float*)d_in[6];
  const float* Wf  = (const float*)d_in[7];
  const float* bf  = (const float*)d_in[8];
  const float* gnw = (const float*)d_in[9];
  const float* gnb = (const float*)d_in[10];

  char* ws = (char*)d_ws;
  unsigned short* Whead = (unsigned short*)ws;
  unsigned short* Wft   = (unsigned short*)(ws + 0x180000);
  unsigned short* xs    = (unsigned short*)(ws + 0x200000);
  unsigned short* obuf  = (unsigned short*)(ws + 0x200000 + (size_t)B_ * S_ * C_ * 2);
  float* out = (float*)d_out;

  hipLaunchKernelGGL(prep, dim3(8448), dim3(256), 0, stream,
                     x, Wq, Wk, Wv, Wf, Whead, Wft, xs);
  hipLaunchKernelGGL(qkvattn, dim3(2048), dim3(512), 0, stream,
                     xs, Whead, bq, bk, bv, obuf);
  hipLaunchKernelGGL(proj_gn, dim3(2048), dim3(512), 0, stream,
                     obuf, Wft, bf, x, gnw, gnb, out);
}

// Round 17
// 312.324 us; speedup vs baseline: 1.0605x; 1.0605x over previous
//
#include <hip/hip_runtime.h>
#include <hip/hip_bf16.h>
#include <stdint.h>

#define B_  256
#define C_  512
#define S_  256
#define NH  8
#define DH  64

typedef float f32x4 __attribute__((ext_vector_type(4)));
typedef short s16x8 __attribute__((ext_vector_type(8)));

static __device__ __forceinline__ unsigned short f2bf(float f) {
  union { float f; unsigned u; } v; v.f = f;
  unsigned r = v.u + 0x7FFFu + ((v.u >> 16) & 1u);
  return (unsigned short)(r >> 16);
}

static __device__ __forceinline__ unsigned pk_bf16(float lo, float hi) {
  unsigned r;
  asm("v_cvt_pk_bf16_f32 %0, %1, %2" : "=v"(r) : "v"(lo), "v"(hi));
  return r;
}

static __device__ __forceinline__ void gload_lds16(const void* g, void* l) {
  __builtin_amdgcn_global_load_lds((const __attribute__((address_space(1))) void*)g,
                                   (__attribute__((address_space(3))) void*)l,
                                   16, 0, 0);
}

// ---- prep (fused): blocks 0..8191 do x->xs transpose; 8192..8447 do W->bf16
__global__ __launch_bounds__(256) void prep(const float* __restrict__ x,
                                            const float* __restrict__ Wq,
                                            const float* __restrict__ Wk,
                                            const float* __restrict__ Wv,
                                            const float* __restrict__ Wf,
                                            unsigned short* __restrict__ Whead,
                                            unsigned short* __restrict__ Wft,
                                            unsigned short* __restrict__ xs) {
  __shared__ float tile[64][65];
  int bid = blockIdx.x;
  int t = threadIdx.x;
  int tr = t >> 4;          // 0..15
  int tc = (t & 15) * 4;    // 0..60
  if (bid < 8192) {
    int b = bid >> 5, rem = bid & 31;
    int s0 = (rem & 3) * 64, c0 = (rem >> 2) * 64;
    const float* xb = x + (size_t)b * C_ * S_;
#pragma unroll
    for (int i = 0; i < 4; ++i) {
      int c = tr + i * 16;
      float4 v = *(const float4*)&xb[(size_t)(c0 + c) * S_ + s0 + tc];
      tile[c][tc + 0] = v.x; tile[c][tc + 1] = v.y;
      tile[c][tc + 2] = v.z; tile[c][tc + 3] = v.w;
    }
    __syncthreads();
    unsigned short* xsb = xs + (size_t)b * S_ * C_;
#pragma unroll
    for (int i = 0; i < 4; ++i) {
      int s = tr + i * 16;
      ushort4 o;
      o.x = f2bf(tile[tc + 0][s]); o.y = f2bf(tile[tc + 1][s]);
      o.z = f2bf(tile[tc + 2][s]); o.w = f2bf(tile[tc + 3][s]);
      *(ushort4*)&xsb[(size_t)(s0 + s) * C_ + c0 + tc] = o;
    }
  } else {
    int r = bid - 8192;
    int mat = r >> 6, r6 = r & 63;
    int n0 = (r6 & 7) * 64, c0 = (r6 >> 3) * 64;
    const float* src = (mat == 0) ? Wq : (mat == 1) ? Wk : (mat == 2) ? Wv : Wf;
#pragma unroll
    for (int i = 0; i < 4; ++i) {
      int c = tr + i * 16;
      float4 v = *(const float4*)&src[(size_t)(c0 + c) * 512 + n0 + tc];
      tile[c][tc + 0] = v.x; tile[c][tc + 1] = v.y;
      tile[c][tc + 2] = v.z; tile[c][tc + 3] = v.w;
    }
    __syncthreads();
    int h = n0 >> 6;
    unsigned short* dst = (mat < 3) ? (Whead + ((size_t)h * 192 + mat * 64) * 512)
                                    : (Wft + (size_t)n0 * 512);
#pragma unroll
    for (int i = 0; i < 4; ++i) {
      int nl = tr + i * 16;
      ushort4 o;
      o.x = f2bf(tile[tc + 0][nl]); o.y = f2bf(tile[tc + 1][nl]);
      o.z = f2bf(tile[tc + 2][nl]); o.w = f2bf(tile[tc + 3][nl]);
      *(ushort4*)&dst[(size_t)nl * 512 + c0 + tc] = o;
    }
  }
}

// ------ qkvattn v6: 1024 threads / 16 waves — 48 AGPR acc, 4 waves/SIMD ---
// Same 256x192 tile, same LDS (114.7KB), same staging bytes as the frozen
// R9 variant; wave tile 64 s x 48 n (4x4 wave grid). Attn: wave owns 16
// q-rows. Registers <=128 -> 4 waves/SIMD co-resident.
#define QKP 68
#define QOFF 0
#define KOFF 34816
#define VOFF 69632
__global__ __launch_bounds__(1024, 4) void qkvattn(const unsigned short* __restrict__ xs,
                                                   const unsigned short* __restrict__ Whead,
                                                   const float* __restrict__ bq,
                                                   const float* __restrict__ bk,
                                                   const float* __restrict__ bv,
                                                   unsigned short* __restrict__ o) {
  __shared__ __align__(16) char lds[114688];
  int bid = blockIdx.x;
  int lin = (bid & 7) * 256 + (bid >> 3);  // XCD-chunked (2048 % 8 == 0)
  int h = lin & 7, b = lin >> 3;
  int t = threadIdx.x, lane = t & 63, w = t >> 6;     // w: 0..15
  int l15 = lane & 15, l4 = lane >> 4;
  int wr = w >> 2, wc = w & 3;             // wave tile: 64 s x 48 n
  const unsigned short* xsb = xs + (size_t)b * S_ * C_;                 // 256 x 512
  const unsigned short* wh  = Whead + (size_t)h * 192 * C_;             // 192 x 512

  // A: 2048 chunks (2/thr); B: 1536 chunks (1/thr + t<512 1 more)
#define FSTAGE(kt, p)                                                         \
  {                                                                           \
    _Pragma("unroll")                                                         \
    for (int i = 0; i < 2; ++i) {                                             \
      int ch = i * 1024 + t, r = ch >> 3, g = ch & 7;                         \
      int gs = g ^ (r & 7);                                                   \
      gload_lds16(xsb + (size_t)r * C_ + (kt) * 64 + gs * 8,                  \
                  lds + (p) * 57344 + ch * 16);                               \
    }                                                                         \
    {                                                                         \
      int ch = t, r = ch >> 3, g = ch & 7;                                    \
      int gs = g ^ (r & 7);                                                   \
      gload_lds16(wh + (size_t)r * C_ + (kt) * 64 + gs * 8,                   \
                  lds + (p) * 57344 + 32768 + ch * 16);                       \
    }                                                                         \
    if (t < 512) {                                                            \
      int ch = 1024 + t, r = ch >> 3, g = ch & 7;                             \
      int gs = g ^ (r & 7);                                                   \
      gload_lds16(wh + (size_t)r * C_ + (kt) * 64 + gs * 8,                   \
                  lds + (p) * 57344 + 32768 + ch * 16);                       \
    }                                                                         \
  }

  f32x4 acc[4][3] = {};
  FSTAGE(0, 0);

  for (int kt = 0; kt < 8; ++kt) {
    if (kt < 7) {
      FSTAGE(kt + 1, (kt + 1) & 1);
      if (t < 512) asm volatile("s_waitcnt vmcnt(4)" ::: "memory");
      else         asm volatile("s_waitcnt vmcnt(3)" ::: "memory");
    } else {
      asm volatile("s_waitcnt vmcnt(0)" ::: "memory");
    }
    __builtin_amdgcn_s_barrier();
    asm volatile("" ::: "memory");
    const char* Ab = lds + (kt & 1) * 57344;
    const char* Bb = Ab + 32768;
#pragma unroll
    for (int kk = 0; kk < 2; ++kk) {
      s16x8 afr[4], bfr[3];
#pragma unroll
      for (int fi = 0; fi < 4; ++fi) {
        int r = wr * 64 + fi * 16 + l15;
        afr[fi] = *(const s16x8*)(Ab + r * 128 + (((kk * 4 + l4) ^ (r & 7)) << 4));
      }
#pragma unroll
      for (int fj = 0; fj < 3; ++fj) {
        int r = wc * 48 + fj * 16 + l15;
        bfr[fj] = *(const s16x8*)(Bb + r * 128 + (((kk * 4 + l4) ^ (r & 7)) << 4));
      }
      __builtin_amdgcn_s_setprio(1);
#pragma unroll
      for (int fi = 0; fi < 4; ++fi)
#pragma unroll
        for (int fj = 0; fj < 3; ++fj)
          acc[fi][fj] = __builtin_amdgcn_mfma_f32_16x16x32_bf16(afr[fi], bfr[fj], acc[fi][fj], 0, 0, 0);
      __builtin_amdgcn_s_setprio(0);
    }
    __builtin_amdgcn_s_barrier();
  }
#undef FSTAGE

  // ---- epilogue: acc+bias -> LDS attn structures ----
  unsigned short* Ql = (unsigned short*)(lds + QOFF);   // [256][68]
  unsigned short* Kl = (unsigned short*)(lds + KOFF);   // [256][68] rho-permuted
  unsigned short* Vl = (unsigned short*)(lds + VOFF);   // [64][264] transposed
  int h64 = h * 64;
#pragma unroll
  for (int fj = 0; fj < 3; ++fj) {
    int n = wc * 48 + fj * 16 + l15;     // sel uniform per (wc,fj)
    int sel = n >> 6, d = n & 63;
    const float* bias = (sel == 0) ? bq : (sel == 1) ? bk : bv;
    float bias_v = bias[h64 + d];
    if (sel == 2) {
#pragma unroll
      for (int fi = 0; fi < 4; ++fi) {
        int s0 = wr * 64 + fi * 16 + l4 * 4;
        ushort4 o4;
        o4.x = f2bf(acc[fi][fj][0] + bias_v);
        o4.y = f2bf(acc[fi][fj][1] + bias_v);
        o4.z = f2bf(acc[fi][fj][2] + bias_v);
        o4.w = f2bf(acc[fi][fj][3] + bias_v);
        *(ushort4*)&Vl[d * 264 + s0] = o4;
      }
    } else {
      unsigned short* dstl = (sel == 0) ? Ql : Kl;
#pragma unroll
      for (int fi = 0; fi < 4; ++fi)
#pragma unroll
        for (int rg = 0; rg < 4; ++rg) {
          int s = wr * 64 + fi * 16 + l4 * 4 + rg;
          int row = s;
          if (sel == 1) {
            int s64 = s & 63, w32 = s64 & 31;
            row = (s & 192) + (s64 >> 5) * 32 + ((w32 >> 2) & 1) * 16 + (w32 >> 3) * 4 + (w32 & 3);
          }
          dstl[row * QKP + d] = f2bf(acc[fi][fj][rg] + bias_v);
        }
    }
  }
  __syncthreads();

  // ---- attn phase: wave w owns q-rows w*16..w*16+15; zero barriers ----
  s16x8 qf[2];
#pragma unroll
  for (int kk = 0; kk < 2; ++kk) {
    int row = w * 16 + l15;
    qf[kk] = *(const s16x8*)((const char*)lds + QOFF + row * (QKP * 2) + kk * 64 + l4 * 16);
  }

  f32x4 acco[4] = {};
  float m_run = -3e38f, l_run = 0.f;
  const float SCL = 0.125f * 1.44269504089f;

  for (int kb = 0; kb < 4; ++kb) {
    f32x4 accs[4] = {};
#pragma unroll
    for (int kk = 0; kk < 2; ++kk) {
      s16x8 kf[4];
#pragma unroll
      for (int fj = 0; fj < 4; ++fj)
        kf[fj] = *(const s16x8*)((const char*)lds + KOFF + (kb * 64 + fj * 16 + l15) * (QKP * 2) + kk * 64 + l4 * 16);
      __builtin_amdgcn_s_setprio(1);
#pragma unroll
      for (int fj = 0; fj < 4; ++fj)
        accs[fj] = __builtin_amdgcn_mfma_f32_16x16x32_bf16(kf[fj], qf[kk], accs[fj], 0, 0, 0);
      __builtin_amdgcn_s_setprio(0);
    }
    {
      float m0[4];
#pragma unroll
      for (int fj = 0; fj < 4; ++fj)
        m0[fj] = fmaxf(fmaxf(accs[fj][0], accs[fj][1]), fmaxf(accs[fj][2], accs[fj][3]));
      float mx = fmaxf(fmaxf(m0[0], m0[1]), fmaxf(m0[2], m0[3]));
      mx = fmaxf(mx, __shfl_xor(mx, 16, 64));
      mx = fmaxf(mx, __shfl_xor(mx, 32, 64));
      float mnew = fmaxf(m_run, mx);
      float alpha = __builtin_amdgcn_exp2f((m_run - mnew) * SCL);
      m_run = mnew;
      float s0[4];
#pragma unroll
      for (int fj = 0; fj < 4; ++fj) {
#pragma unroll
        for (int rg = 0; rg < 4; ++rg) {
          float p = __builtin_amdgcn_exp2f((accs[fj][rg] - mnew) * SCL);
          accs[fj][rg] = p;
        }
        s0[fj] = (accs[fj][0] + accs[fj][1]) + (accs[fj][2] + accs[fj][3]);
      }
      float lsum = (s0[0] + s0[1]) + (s0[2] + s0[3]);
      lsum += __shfl_xor(lsum, 16, 64);
      lsum += __shfl_xor(lsum, 32, 64);
      l_run = l_run * alpha + lsum;
#pragma unroll
      for (int fd = 0; fd < 4; ++fd)
#pragma unroll
        for (int rg = 0; rg < 4; ++rg) acco[fd][rg] *= alpha;
    }
#pragma unroll
    for (int kk2 = 0; kk2 < 2; ++kk2) {
      s16x8 vf[4];
#pragma unroll
      for (int fd = 0; fd < 4; ++fd)
        vf[fd] = *(const s16x8*)((const char*)lds + VOFF + (fd * 16 + l15) * 528 + kb * 128 + kk2 * 64 + l4 * 16);
      union { unsigned u[4]; s16x8 v; } pb;
      pb.u[0] = pk_bf16(accs[2 * kk2][0],     accs[2 * kk2][1]);
      pb.u[1] = pk_bf16(accs[2 * kk2][2],     accs[2 * kk2][3]);
      pb.u[2] = pk_bf16(accs[2 * kk2 + 1][0], accs[2 * kk2 + 1][1]);
      pb.u[3] = pk_bf16(accs[2 * kk2 + 1][2], accs[2 * kk2 + 1][3]);
      __builtin_amdgcn_s_setprio(1);
#pragma unroll
      for (int fd = 0; fd < 4; ++fd)
        acco[fd] = __builtin_amdgcn_mfma_f32_16x16x32_bf16(vf[fd], pb.v, acco[fd], 0, 0, 0);
      __builtin_amdgcn_s_setprio(0);
    }
  }

  unsigned short* ob = o + (size_t)b * S_ * C_ + h * DH;
  {
    float inv = 1.0f / l_run;
    int qrow = w * 16 + l15;
#pragma unroll
    for (int fd = 0; fd < 4; ++fd) {
      ushort4 s4;
      s4.x = f2bf(acco[fd][0] * inv);
      s4.y = f2bf(acco[fd][1] * inv);
      s4.z = f2bf(acco[fd][2] * inv);
      s4.w = f2bf(acco[fd][3] * inv);
      *(ushort4*)&ob[(size_t)qrow * C_ + fd * 16 + l4 * 4] = s4;
    }
  }
}

// ------- proj_gn v6 (R13-best): 64c x 256s, 40KB LDS ----------------------
__global__ __launch_bounds__(512, 4) void proj_gn(const unsigned short* __restrict__ o,
                                                  const unsigned short* __restrict__ Wft,
                                                  const float* __restrict__ bfp,
                                                  const float* __restrict__ x,
                                                  const float* __restrict__ gnw,
                                                  const float* __restrict__ gnb,
                                                  float* __restrict__ out) {
  __shared__ __align__(16) char plds[40960];
  __shared__ float red_s[64], red_q[64];
  __shared__ float mu_s[4], rs_s[4];
  int bid = blockIdx.x;
  int lin = (bid & 7) * 256 + (bid >> 3);
  int b = lin >> 3, ct = lin & 7;
  int t = threadIdx.x, lane = t & 63, w = t >> 6;
  int l15 = lane & 15, l4 = lane >> 4;
  if (t < 64) { red_s[t] = 0.f; red_q[t] = 0.f; }
  f32x4 acc[4][2] = {};
  const unsigned short* wt = Wft + (size_t)ct * 64 * C_;
  const unsigned short* ob = o + (size_t)b * S_ * C_;

#define PSTAGE(kt, p)                                                         \
  {                                                                           \
    if (t < 256) {                                                            \
      int r = t >> 2, g = t & 3;                                              \
      int gs = g ^ ((r >> 1) & 3);                                            \
      gload_lds16(wt + (size_t)r * C_ + (kt) * 32 + gs * 8,                   \
                  plds + (p) * 20480 + t * 16);                               \
    }                                                                         \
    _Pragma("unroll")                                                         \
    for (int i = 0; i < 2; ++i) {                                             \
      int ch = i * 512 + t, r = ch >> 2, g = ch & 3;                          \
      int gs = g ^ ((r >> 1) & 3);                                            \
      gload_lds16(ob + (size_t)r * C_ + (kt) * 32 + gs * 8,                   \
                  plds + (p) * 20480 + 4096 + ch * 16);                       \
    }                                                                         \
  }

  PSTAGE(0, 0);

  for (int kt = 0; kt < 16; ++kt) {
    if (kt < 15) {
      PSTAGE(kt + 1, (kt + 1) & 1);
      if (t < 256) asm volatile("s_waitcnt vmcnt(3)" ::: "memory");
      else         asm volatile("s_waitcnt vmcnt(2)" ::: "memory");
    } else {
      asm volatile("s_waitcnt vmcnt(0)" ::: "memory");
    }
    __builtin_amdgcn_s_barrier();
    asm volatile("" ::: "memory");
    const char* Ab = plds + (kt & 1) * 20480;
    const char* Bb = Ab + 4096;
    s16x8 af[4], bfr[2];
#pragma unroll
    for (int fi = 0; fi < 4; ++fi) {
      int r = fi * 16 + l15;
      af[fi] = *(const s16x8*)(Ab + r * 64 + ((l4 ^ ((r >> 1) & 3)) << 4));
    }
#pragma unroll
    for (int fj = 0; fj < 2; ++fj) {
      int r = w * 32 + fj * 16 + l15;
      bfr[fj] = *(const s16x8*)(Bb + r * 64 + ((l4 ^ ((r >> 1) & 3)) << 4));
    }
    __builtin_amdgcn_s_setprio(1);
#pragma unroll
    for (int fi = 0; fi < 4; ++fi)
#pragma unroll
      for (int fj = 0; fj < 2; ++fj)
        acc[fi][fj] = __builtin_amdgcn_mfma_f32_16x16x32_bf16(af[fi], bfr[fj], acc[fi][fj], 0, 0, 0);
    __builtin_amdgcn_s_setprio(0);
    __builtin_amdgcn_s_barrier();
  }
#undef PSTAGE

  const float* xb = x + (size_t)b * C_ * S_;
  int c_base = ct * 64;
  int s_base = w * 32;
#pragma unroll
  for (int fi = 0; fi < 4; ++fi)
#pragma unroll
    for (int rg = 0; rg < 4; ++rg) {
      int cl = fi * 16 + l4 * 4 + rg;
      int c = c_base + cl;
      float bias_v = bfp[c];
      float psum = 0.f, psq = 0.f;
#pragma unroll
      for (int fj = 0; fj < 2; ++fj) {
        int s = s_base + fj * 16 + l15;
        float y = acc[fi][fj][rg] + bias_v + xb[(size_t)c * S_ + s];
        acc[fi][fj][rg] = y;
        psum += y; psq += y * y;
      }
#pragma unroll
      for (int off = 1; off < 16; off <<= 1) {
        psum += __shfl_xor(psum, off, 64);
        psq += __shfl_xor(psq, off, 64);
      }
      if (l15 == 0) {
        atomicAdd(&red_s[cl], psum);
        atomicAdd(&red_q[cl], psq);
      }
    }
  __syncthreads();
  if (t < 4) {
    float s = 0.f, qq = 0.f;
#pragma unroll
    for (int i = 0; i < 16; ++i) { s += red_s[t * 16 + i]; qq += red_q[t * 16 + i]; }
    float mu = s * (1.0f / 4096.0f);
    float var = qq * (1.0f / 4096.0f) - mu * mu;
    mu_s[t] = mu;
    rs_s[t] = rsqrtf(var + 1e-5f);
  }
  __syncthreads();
  float* outb = out + (size_t)b * C_ * S_;
#pragma unroll
  for (int fi = 0; fi < 4; ++fi)
#pragma unroll
    for (int rg = 0; rg < 4; ++rg) {
      int cl = fi * 16 + l4 * 4 + rg;
      int c = c_base + cl;
      int gl = cl >> 4;
      float mu = mu_s[gl], rs = rs_s[gl];
      float gw = gnw[c], gb = gnb[c];
#pragma unroll
      for (int fj = 0; fj < 2; ++fj) {
        int s = s_base + fj * 16 + l15;
        outb[(size_t)c * S_ + s] = (acc[fi][fj][rg] - mu) * rs * gw + gb;
      }
    }
}

extern "C" void kernel_launch(void* const* d_in, const int* in_sizes, int n_in,
                              void* d_out, int out_size, void* d_ws, size_t ws_size,
                              hipStream_t stream) {
  const float* x   = (const float*)d_in[0];
  const float* Wq  = (const float*)d_in[1];
  const float* bq  = (const float*)d_in[2];
  const float* Wk  = (const float*)d_in[3];
  const float* bk  = (const float*)d_in[4];
  const float* Wv  = (const float*)d_in[5];
  const float* bv  = (const float*)d_in[6];
  const float* Wf  = (const float*)d_in[7];
  const float* bf  = (const float*)d_in[8];
  const float* gnw = (const float*)d_in[9];
  const float* gnb = (const float*)d_in[10];

  char* ws = (char*)d_ws;
  unsigned short* Whead = (unsigned short*)ws;
  unsigned short* Wft   = (unsigned short*)(ws + 0x180000);
  unsigned short* xs    = (unsigned short*)(ws + 0x200000);
  unsigned short* obuf  = (unsigned short*)(ws + 0x200000 + (size_t)B_ * S_ * C_ * 2);
  float* out = (float*)d_out;

  hipLaunchKernelGGL(prep, dim3(8448), dim3(256), 0, stream,
                     x, Wq, Wk, Wv, Wf, Whead, Wft, xs);
  hipLaunchKernelGGL(qkvattn, dim3(2048), dim3(1024), 0, stream,
                     xs, Whead, bq, bk, bv, obuf);
  hipLaunchKernelGGL(proj_gn, dim3(2048), dim3(512), 0, stream,
                     obuf, Wft, bf, x, gnw, gnb, out);
}